// Round 6
// baseline (490.021 us; speedup 1.0000x reference)
//
#include <hip/hip_runtime.h>
#include <math.h>

#define BSZ 8
#define KG  8
#define NP  16
#define MM  64            // BS*K
#define TT  3072
#define WGN 64
#define HH  256
#define WCN 256
#define RHN 1024
#define RWN 512

#define C1H 1024
#define C1W 31
#define C2H 341
#define C2W 15
#define C3H 113
#define C3W 7

#define N1 (MM*C1H*C1W)               // 2,031,616
#define N2 (MM*C2H*C2W)               // 327,360 (per channel)
#define N3 (MM*C3H*C3W)               // 50,624
#define NF (BSZ*RHN*RWN)              // 4,194,304

// ---- DIAGNOSTIC repeat factors (idempotent re-execution to surface each
// kernel in rocprof's top-5, which is otherwise swamped by 41.7us fills).
// Revert all to 1 after reading the counters.
#define REP2 16
#define REP3 24
#define REP5 8
#define REP6 8

// ---- grids (fixed: partial-slot counts depend on them) ----
#define G1 1024
#define G2 704                        // MM * ceil(341/32)
#define G3 256
#define G5 512
#define G6 512

// ---- partial-sum slots (doubles), plain stores - no atomics, no memset ----
#define P1S   0
#define P1SS  1024
#define P2S0  2048
#define P2SS0 2752
#define P2S1  3456
#define P2SS1 4160
#define P3S   4864
#define P3SS  5120
#define PFS   5376
#define PFSS  5888
// total 6400 doubles = 51200 B

#define OFF_VINT 51200
#define OFF_Y1   (OFF_VINT + MM*HH*4)
#define OFF_Y2   (OFF_Y1  + N1*4)
#define OFF_Y3   (OFF_Y2  + 2*N2*4)
#define OFF_Y5   (OFF_Y3  + N3*4)

#define K1_R 16
#define K1_ROWS (3*K1_R)             // 48 input rows
#define K1_CH 4
#define F2_OH 32
#define F2_NCH 11                    // ceil(341/32)
#define F2_NRMAX (3*F2_OH + 4)       // 100
#define MC_TH 16

// block-reduce (s,ss) then ONE plain store per block into slot bid.
__device__ __forceinline__ void blockStore2(double s, double ss,
                                            double* __restrict__ o0,
                                            double* __restrict__ o1) {
    __shared__ double red[4][2];
    __syncthreads();
    int lane = threadIdx.x & 63, wid = threadIdx.x >> 6;
#pragma unroll
    for (int off = 32; off > 0; off >>= 1) {
        s  += __shfl_down(s,  off, 64);
        ss += __shfl_down(ss, off, 64);
    }
    if (lane == 0) { red[wid][0] = s; red[wid][1] = ss; }
    __syncthreads();
    if (threadIdx.x == 0) {
        double a = 0, b = 0;
#pragma unroll
        for (int i = 0; i < 4; i++) { a += red[i][0]; b += red[i][1]; }
        o0[blockIdx.x] = a; o1[blockIdx.x] = b;
    }
}

// 4-wave parallel BN fold: all 256 threads reduce npart partials; thread 0
// folds and writes (a,b) to *outsh. Self-synced: safe to read *outsh after.
__device__ __forceinline__ void bn_fold4(const double* __restrict__ ps,
                                         const double* __restrict__ pss,
                                         int npart, const float* __restrict__ g, int gc,
                                         const float* __restrict__ be,
                                         double n, float2* outsh) {
    __shared__ double red4[4][2];
    int lane = threadIdx.x & 63, wid = threadIdx.x >> 6;
    double s = 0, ss = 0;
    for (int i = threadIdx.x; i < npart; i += 256) { s += ps[i]; ss += pss[i]; }
#pragma unroll
    for (int off = 32; off > 0; off >>= 1) {
        s  += __shfl_down(s,  off, 64);
        ss += __shfl_down(ss, off, 64);
    }
    if (lane == 0) { red4[wid][0] = s; red4[wid][1] = ss; }
    __syncthreads();
    if (threadIdx.x == 0) {
        double a = red4[0][0] + red4[1][0] + red4[2][0] + red4[3][0];
        double b = red4[0][1] + red4[1][1] + red4[2][1] + red4[3][1];
        double mean = a / n;
        double var  = b / n - mean * mean;
        double sc = (double)g[gc] / sqrt(var + 1e-5);
        *outsh = make_float2((float)sc, (float)((double)be[gc] - mean * sc));
    }
    __syncthreads();
}

// ---- K1: conv1 (1x1x3x3, stride 3x2, VALID) + BN1 partials; blocks 0..63
// also compute vint. x/absmax(x) norm and b1 dropped (absorbed by BN1). ----
__global__ void k_conv1(const float* __restrict__ g, const float* __restrict__ cv,
                        const float* __restrict__ VMM, const float* __restrict__ w1,
                        const float* __restrict__ b1,
                        float* __restrict__ y1, int* __restrict__ vint,
                        double* __restrict__ sums) {
    __shared__ float sm[K1_ROWS * WGN];       // 12 KB
    __shared__ float tt[NP], vv[NP];
    int m  = blockIdx.x >> 4;
    int bg = blockIdx.x & 15;
    const float4* src0 = (const float4*)(g + (size_t)m * TT * WGN
                                           + (size_t)(bg * K1_CH * K1_R * 3) * WGN);
    float w[9];
#pragma unroll
    for (int i = 0; i < 9; i++) w[i] = w1[i];
    float bb = b1[0];
    float4 ra0, ra1, ra2, rb0, rb1, rb2;
    ra0 = src0[threadIdx.x];
    ra1 = src0[threadIdx.x + 256];
    ra2 = src0[threadIdx.x + 512];
    double s = 0, ss = 0;
    float4* dst = (float4*)sm;
#pragma unroll
    for (int i = 0; i < K1_CH; i++) {
        if (i & 1) {
            dst[threadIdx.x]       = rb0;
            dst[threadIdx.x + 256] = rb1;
            dst[threadIdx.x + 512] = rb2;
        } else {
            dst[threadIdx.x]       = ra0;
            dst[threadIdx.x + 256] = ra1;
            dst[threadIdx.x + 512] = ra2;
        }
        __syncthreads();
        if (i + 1 < K1_CH) {
            const float4* srcn = src0 + (size_t)(i + 1) * 768;
            if (i & 1) {
                ra0 = srcn[threadIdx.x];
                ra1 = srcn[threadIdx.x + 256];
                ra2 = srcn[threadIdx.x + 512];
            } else {
                rb0 = srcn[threadIdx.x];
                rb1 = srcn[threadIdx.x + 256];
                rb2 = srcn[threadIdx.x + 512];
            }
        }
        int oh0 = (bg * K1_CH + i) * K1_R;
        float* yb = y1 + (size_t)m * C1H * C1W + (size_t)oh0 * C1W;
        for (int o = threadIdx.x; o < K1_R * C1W; o += 256) {
            int lo = o / C1W, ow = o % C1W;
            const float* xp = sm + (3 * lo) * WGN + ow * 2;
            float acc = bb;
#pragma unroll
            for (int r = 0; r < 3; r++)
#pragma unroll
                for (int c = 0; c < 3; c++) acc += w[r * 3 + c] * xp[r * WGN + c];
            yb[o] = acc;
            s += acc; ss += (double)acc * (double)acc;
        }
        __syncthreads();
    }
    if (blockIdx.x < MM) {
        int mv = blockIdx.x;
        int b = mv >> 3;
        if (threadIdx.x < NP) {
            int n = threadIdx.x;
            float t = cv[(mv * NP + n) * 2 + 0];
            float v = cv[(mv * NP + n) * 2 + 1];
            float dt = 7000.0f / 255.0f;
            tt[n] = t / dt;
            float vmin = VMM[b * 2], vmax = VMM[b * 2 + 1];
            float dv = (vmax - vmin) / 255.0f;
            vv[n] = (v - vmin) / dv;
        }
        __syncthreads();
        int h = threadIdx.x;
        float x = (float)h;
        float val;
        if (x <= tt[0]) val = vv[0];
        else if (x >= tt[NP - 1]) val = vv[NP - 1];
        else {
            int i = 1;
            while (i < NP - 1 && tt[i] <= x) i++;
            float d = tt[i] - tt[i - 1];
            val = (d != 0.f) ? vv[i - 1] + (x - tt[i - 1]) / d * (vv[i] - vv[i - 1]) : vv[i];
        }
        int vi = (int)val;
        vint[mv * HH + h] = max(0, min(WCN - 1, vi));
    }
    blockStore2(s, ss, &sums[P1S], &sums[P1SS]);
}

// ---- K2: BN1-act + maxpool3/5 (separable, LDS) + conv2 + BN2 partials ----
__global__ void k_fused2(const float* __restrict__ y1, const double* __restrict__ sums_r,
                         const float* __restrict__ g1, const float* __restrict__ be1,
                         const float* __restrict__ w2, const float* __restrict__ b2,
                         float* __restrict__ y2, double* __restrict__ sums) {
    __shared__ float sact[F2_NRMAX][32];
    __shared__ float sr3[F2_NRMAX][32];
    __shared__ float sr5[F2_NRMAX][32];
    __shared__ float2 absh;
    int m   = blockIdx.x / F2_NCH;
    int ch  = blockIdx.x % F2_NCH;
    int oh0 = ch * F2_OH;
    int OHa = min(F2_OH, C2H - oh0);
    int NR  = 3 * OHa + 4;
    int gl0 = 3 * oh0 - 2;
    const float* yp = y1 + (size_t)m * C1H * C1W;
    for (int rep = 0; rep < REP2; ++rep) {
        bn_fold4(&sums_r[P1S], &sums_r[P1SS], G1, g1, 0, be1, (double)N1, &absh);
        float2 ab1 = absh;
        for (int i = threadIdx.x; i < NR * C1W; i += blockDim.x) {
            int l = i / C1W, w = i % C1W;
            int gr = gl0 + l;
            float v = -INFINITY;
            if (gr >= 0 && gr < C1H) {
                v = ab1.x * yp[gr * C1W + w] + ab1.y;
                v = v >= 0.f ? v : 0.1f * v;
            }
            sact[l][w] = v;
        }
        __syncthreads();
        for (int i = threadIdx.x; i < NR * C1W; i += blockDim.x) {
            int l = i / C1W, w = i % C1W;
            int wl1 = max(w - 1, 0), wr1 = min(w + 1, C1W - 1);
            int wl2 = max(w - 2, 0), wr2 = min(w + 2, C1W - 1);
            float c  = sact[l][w];
            float m3 = fmaxf(fmaxf(sact[l][wl1], c), sact[l][wr1]);
            float m5 = fmaxf(fmaxf(m3, sact[l][wl2]), sact[l][wr2]);
            sr3[l][w] = m3;
            sr5[l][w] = m5;
        }
        __syncthreads();
        double s0 = 0, ss0 = 0, s1 = 0, ss1 = 0;
        for (int o = threadIdx.x; o < OHa * C2W; o += blockDim.x) {
            int lo = o / C2W, ow = o % C2W;
            float a0 = b2[0], acc1 = b2[1];
#pragma unroll
            for (int i = 0; i < 3; i++) {
                int l = 3 * lo + 2 + i;
#pragma unroll
                for (int j = 0; j < 3; j++) {
                    int wc = 2 * ow + j;
                    float v0 = sact[l][wc];
                    float v1 = fmaxf(fmaxf(sr3[l - 1][wc], sr3[l][wc]), sr3[l + 1][wc]);
                    float v2 = fmaxf(fmaxf(fmaxf(sr5[l - 2][wc], sr5[l - 1][wc]), sr5[l][wc]),
                                     fmaxf(sr5[l + 1][wc], sr5[l + 2][wc]));
                    int ki = i * 3 + j;
                    a0   += w2[ki] * v0 + w2[9 + ki] * v1 + w2[18 + ki] * v2;
                    acc1 += w2[27 + ki] * v0 + w2[36 + ki] * v1 + w2[45 + ki] * v2;
                }
            }
            size_t ob = (size_t)m * (2 * C2H * C2W) + (size_t)(oh0 + lo) * C2W + ow;
            y2[ob] = a0;
            y2[ob + C2H * C2W] = acc1;
            s0 += a0; ss0 += (double)a0 * a0;
            s1 += acc1; ss1 += (double)acc1 * acc1;
        }
        blockStore2(s0, ss0, &sums[P2S0], &sums[P2SS0]);
        blockStore2(s1, ss1, &sums[P2S1], &sums[P2SS1]);
        __syncthreads();
    }
}

// ---- K3: conv3 (1x2x3x2, stride 3x2), BN2-act inline + BN3 partials ----
__global__ void k_conv3(const float* __restrict__ y2, const double* __restrict__ sums_r,
                        const float* __restrict__ g2, const float* __restrict__ be2,
                        const float* __restrict__ w3, const float* __restrict__ b3,
                        float* __restrict__ y3, double* __restrict__ sums) {
    __shared__ float2 absh[2];
    for (int rep = 0; rep < REP3; ++rep) {
        bn_fold4(&sums_r[P2S0], &sums_r[P2SS0], G2, g2, 0, be2, (double)N2, &absh[0]);
        bn_fold4(&sums_r[P2S1], &sums_r[P2SS1], G2, g2, 1, be2, (double)N2, &absh[1]);
        float2 ab20 = absh[0], ab21 = absh[1];
        double s = 0, ss = 0;
        int idx = blockIdx.x * 256 + threadIdx.x;
        if (idx < N3) {
            int ow = idx % C3W;
            int t2 = idx / C3W;
            int oh = t2 % C3H;
            int m  = t2 / C3H;
            float acc = b3[0];
#pragma unroll
            for (int i = 0; i < 2; i++) {
                float aa = i ? ab21.x : ab20.x, bb = i ? ab21.y : ab20.y;
                const float* cp = y2 + (size_t)m * (2 * C2H * C2W) + (size_t)i * C2H * C2W
                                  + (size_t)(oh * 3) * C2W + ow * 2;
#pragma unroll
                for (int r = 0; r < 3; r++)
#pragma unroll
                    for (int c = 0; c < 2; c++) {
                        float v = aa * cp[r * C2W + c] + bb;
                        v = v >= 0.f ? v : 0.1f * v;
                        acc += w3[i * 6 + r * 2 + c] * v;
                    }
            }
            y3[idx] = acc;
            s = acc; ss = (double)acc * acc;
        }
        blockStore2(s, ss, &sums[P3S], &sums[P3SS]);
        __syncthreads();
    }
}

// ---- K5a: genr-on-the-fly -> mix tile -> convf -> y5 + BNf partials ----
__global__ void k_mixA(const float* __restrict__ y3, const int* __restrict__ vint,
                       const double* __restrict__ sums_r,
                       const float* __restrict__ g3, const float* __restrict__ be3,
                       const float* __restrict__ wf, const float* __restrict__ bf,
                       float* __restrict__ y5, double* __restrict__ sums) {
    __shared__ float tile[MC_TH + 2][RWN + 2];
    __shared__ float Grow[MC_TH + 2];
    __shared__ float2 absh;
    int b   = blockIdx.x / (RHN / MC_TH);
    int h0  = (blockIdx.x % (RHN / MC_TH)) * MC_TH;
    for (int rep = 0; rep < REP5; ++rep) {
        bn_fold4(&sums_r[P3S], &sums_r[P3SS], G3, g3, 0, be3, (double)N3, &absh);
        float2 ab3 = absh;
        for (int i = threadIdx.x; i < (MC_TH + 2) * (RWN + 2); i += 256)
            ((float*)tile)[i] = 0.f;
        if (threadIdx.x < MC_TH + 2) Grow[threadIdx.x] = 0.f;
        __syncthreads();
        if (threadIdx.x < (MC_TH + 2) * KG) {
            int r = threadIdx.x / KG, k = threadIdx.x % KG;
            int h = h0 - 1 + r;
            if (h >= 0 && h < RHN) {
                int m = b * KG + k;
                const float cw0 = 4.f / 37.f, cw1 = 5.f / 37.f, cw2 = 6.f / 37.f, cw3 = 7.f / 37.f;
                const float cw[7] = { cw0, cw1, cw2, cw3, cw2, cw1, cw0 };
                float shg = (h + 0.5f) * (113.0f / 1024.0f) - 0.5f;
                float flg = floorf(shg);
                float frg = shg - flg;
                int gi0 = (int)flg, gi1 = gi0 + 1;
                gi0 = max(0, min(C3H - 1, gi0));
                gi1 = max(0, min(C3H - 1, gi1));
                const float* yp0 = y3 + (size_t)m * (C3H * C3W) + gi0 * C3W;
                const float* yp1 = y3 + (size_t)m * (C3H * C3W) + gi1 * C3W;
                float g = 0.f;
#pragma unroll
                for (int x = 0; x < 7; x++) {
                    float t0 = ab3.x * yp0[x] + ab3.y;
                    t0 = t0 >= 0.f ? t0 : 0.1f * t0;
                    float t1 = ab3.x * yp1[x] + ab3.y;
                    t1 = t1 >= 0.f ? t1 : 0.1f * t1;
                    g += cw[x] * ((1.f - frg) * t0 + frg * t1);
                }
                atomicAdd(&Grow[r], g);
                float sh = (h + 0.5f) * 0.25f - 0.5f;
                float fl = floorf(sh);
                float fh = sh - fl;
                int ih0 = (int)fl, ih1 = ih0 + 1;
                ih0 = max(0, min(HH - 1, ih0));
                ih1 = max(0, min(HH - 1, ih1));
                int vv2[2] = { vint[m * HH + ih0], vint[m * HH + ih1] };
                float aa[2] = { 0.9f * g * (1.f - fh), 0.9f * g * fh };
#pragma unroll
                for (int t = 0; t < 2; t++) {
                    int v = vv2[t]; float A = aa[t];
                    if (v == 0) {
                        atomicAdd(&tile[r][1 + 0], A);
                        atomicAdd(&tile[r][1 + 1], 0.75f * A);
                        atomicAdd(&tile[r][1 + 2], 0.25f * A);
                    } else if (v == WCN - 1) {
                        atomicAdd(&tile[r][1 + 509], 0.25f * A);
                        atomicAdd(&tile[r][1 + 510], 0.75f * A);
                        atomicAdd(&tile[r][1 + 511], A);
                    } else {
                        atomicAdd(&tile[r][1 + 2 * v - 1], 0.25f * A);
                        atomicAdd(&tile[r][1 + 2 * v],     0.75f * A);
                        atomicAdd(&tile[r][1 + 2 * v + 1], 0.75f * A);
                        atomicAdd(&tile[r][1 + 2 * v + 2], 0.25f * A);
                    }
                }
            }
        }
        __syncthreads();
        for (int i = threadIdx.x; i < (MC_TH + 2) * RWN; i += 256) {
            int r = i / RWN, w = i % RWN;
            int h = h0 - 1 + r;
            if (h >= 0 && h < RHN) tile[r][w + 1] += 0.01f * Grow[r];
        }
        __syncthreads();
        float w[9];
#pragma unroll
        for (int i = 0; i < 9; i++) w[i] = wf[i];
        float bb = bf[0];
        double s = 0, ss = 0;
        for (int o = threadIdx.x; o < MC_TH * RWN; o += 256) {
            int lr = o >> 9, x = o & (RWN - 1);
            float acc = bb;
#pragma unroll
            for (int dr = 0; dr < 3; dr++)
#pragma unroll
                for (int dc = 0; dc < 3; dc++)
                    acc += w[dr * 3 + dc] * tile[lr + dr][x + dc];
            y5[((size_t)b * RHN + (h0 + lr)) * RWN + x] = acc;
            s += acc; ss += (double)acc * acc;
        }
        blockStore2(s, ss, &sums[PFS], &sums[PFSS]);
        __syncthreads();
    }
}

// ---- K5b: BNf affine + LReLU over y5 -> out (vectorized) ----
__global__ void k_bnf(const float* __restrict__ y5, const double* __restrict__ sums_r,
                      const float* __restrict__ gf, const float* __restrict__ bef,
                      float* __restrict__ out) {
    __shared__ float2 absh;
    for (int rep = 0; rep < REP6; ++rep) {
        bn_fold4(&sums_r[PFS], &sums_r[PFSS], G5, gf, 0, bef, (double)NF, &absh);
        float2 abf = absh;
        const float4* src = (const float4*)y5;
        float4* dst = (float4*)out;
        int base = blockIdx.x * 256 + threadIdx.x;
#pragma unroll
        for (int j = 0; j < 8; j++) {
            int i = base + j * (G6 * 256);
            float4 v = src[i];
            float a0 = abf.x * v.x + abf.y;
            float a1 = abf.x * v.y + abf.y;
            float a2 = abf.x * v.z + abf.y;
            float a3 = abf.x * v.w + abf.y;
            v.x = a0 >= 0.f ? a0 : 0.1f * a0;
            v.y = a1 >= 0.f ? a1 : 0.1f * a1;
            v.z = a2 >= 0.f ? a2 : 0.1f * a2;
            v.w = a3 >= 0.f ? a3 : 0.1f * a3;
            dst[i] = v;
        }
        __syncthreads();
    }
}

extern "C" void kernel_launch(void* const* d_in, const int* in_sizes, int n_in,
                              void* d_out, int out_size, void* d_ws, size_t ws_size,
                              hipStream_t stream) {
    const float* gather = (const float*)d_in[0];
    const float* cv     = (const float*)d_in[1];
    const float* VMM    = (const float*)d_in[2];
    const float* w1 = (const float*)d_in[3];
    const float* b1 = (const float*)d_in[4];
    const float* g1 = (const float*)d_in[5];
    const float* be1 = (const float*)d_in[6];
    const float* w2 = (const float*)d_in[7];
    const float* b2 = (const float*)d_in[8];
    const float* g2 = (const float*)d_in[9];
    const float* be2 = (const float*)d_in[10];
    const float* w3 = (const float*)d_in[11];
    const float* b3 = (const float*)d_in[12];
    const float* g3 = (const float*)d_in[13];
    const float* be3 = (const float*)d_in[14];
    const float* wf = (const float*)d_in[15];
    const float* bf = (const float*)d_in[16];
    const float* gf = (const float*)d_in[17];
    const float* bef = (const float*)d_in[18];
    float* out = (float*)d_out;

    char* ws = (char*)d_ws;
    double* sums = (double*)ws;
    int*   vint  = (int*)(ws + OFF_VINT);
    float* y1    = (float*)(ws + OFF_Y1);
    float* y2    = (float*)(ws + OFF_Y2);
    float* y3    = (float*)(ws + OFF_Y3);
    float* y5    = (float*)(ws + OFF_Y5);

    k_conv1<<<G1, 256, 0, stream>>>(gather, cv, VMM, w1, b1, y1, vint, sums);
    k_fused2<<<G2, 256, 0, stream>>>(y1, sums, g1, be1, w2, b2, y2, sums);
    k_conv3<<<G3, 256, 0, stream>>>(y2, sums, g2, be2, w3, b3, y3, sums);
    k_mixA<<<G5, 256, 0, stream>>>(y3, vint, sums, g3, be3, wf, bf, y5, sums);
    k_bnf<<<G6, 256, 0, stream>>>(y5, sums, gf, bef, out);
}

// Round 7
// 173.580 us; speedup vs baseline: 2.8230x; 2.8230x over previous
//
#include <hip/hip_runtime.h>
#include <math.h>

#define BSZ 8
#define KG  8
#define NP  16
#define MM  64            // BS*K
#define TT  3072
#define WGN 64
#define HH  256
#define WCN 256
#define RHN 1024
#define RWN 512

#define C1H 1024
#define C1W 31
#define C2H 341
#define C2W 15
#define C3H 113
#define C3W 7

#define N1 (MM*C1H*C1W)               // 2,031,616
#define N2 (MM*C2H*C2W)               // 327,360 (per channel)
#define N3 (MM*C3H*C3W)               // 50,624
#define NF (BSZ*RHN*RWN)              // 4,194,304

// ---- grids (fixed: partial-slot counts depend on them) ----
#define G1 1024
#define G2 1408                       // MM * ceil(341/16)
#define G3 256
#define G5 1024
#define G6 512

// ---- partial-sum slots (doubles), plain stores - no atomics, no memset ----
#define P1S   0
#define P1SS  1024
#define P2S0  2048
#define P2SS0 3456
#define P2S1  4864
#define P2SS1 6272
#define P3S   7680
#define P3SS  7936
#define PFS   8192
#define PFSS  9216
// total 10240 doubles = 81920 B

#define OFF_VINT 81920
#define OFF_Y1   (OFF_VINT + MM*HH*4)
#define OFF_Y2   (OFF_Y1  + N1*4)
#define OFF_Y3   (OFF_Y2  + 2*N2*4)
#define OFF_Y5   (OFF_Y3  + N3*4)

#define K1_R 16
#define K1_ROWS (3*K1_R)             // 48 input rows
#define K1_CH 4
#define F2_OH 16
#define F2_NCH 22                    // ceil(341/16)
#define F2_NRMAX (3*F2_OH + 4)       // 52
#define F2_PAD 33                    // row pad: break even-bank stride-2 conflicts
#define MC_TH 8

// block-reduce (s,ss) then ONE plain store per block into slot bid.
__device__ __forceinline__ void blockStore2(double s, double ss,
                                            double* __restrict__ o0,
                                            double* __restrict__ o1) {
    __shared__ double red[4][2];
    __syncthreads();
    int lane = threadIdx.x & 63, wid = threadIdx.x >> 6;
#pragma unroll
    for (int off = 32; off > 0; off >>= 1) {
        s  += __shfl_down(s,  off, 64);
        ss += __shfl_down(ss, off, 64);
    }
    if (lane == 0) { red[wid][0] = s; red[wid][1] = ss; }
    __syncthreads();
    if (threadIdx.x == 0) {
        double a = 0, b = 0;
        int nw = blockDim.x >> 6;
        for (int i = 0; i < nw; i++) { a += red[i][0]; b += red[i][1]; }
        o0[blockIdx.x] = a; o1[blockIdx.x] = b;
    }
}

// 4-wave parallel BN fold: all threads reduce npart partials; thread 0 folds
// and writes (a,b) to *outsh. Self-synced: safe to read *outsh on return.
__device__ __forceinline__ void bn_fold4(const double* __restrict__ ps,
                                         const double* __restrict__ pss,
                                         int npart, const float* __restrict__ g, int gc,
                                         const float* __restrict__ be,
                                         double n, float2* outsh) {
    __shared__ double red4[4][2];
    int lane = threadIdx.x & 63, wid = threadIdx.x >> 6;
    double s = 0, ss = 0;
    for (int i = threadIdx.x; i < npart; i += blockDim.x) { s += ps[i]; ss += pss[i]; }
#pragma unroll
    for (int off = 32; off > 0; off >>= 1) {
        s  += __shfl_down(s,  off, 64);
        ss += __shfl_down(ss, off, 64);
    }
    if (lane == 0) { red4[wid][0] = s; red4[wid][1] = ss; }
    __syncthreads();
    if (threadIdx.x == 0) {
        double a = 0, b = 0;
        int nw = blockDim.x >> 6;
        for (int i = 0; i < nw; i++) { a += red4[i][0]; b += red4[i][1]; }
        double mean = a / n;
        double var  = b / n - mean * mean;
        double sc = (double)g[gc] / sqrt(var + 1e-5);
        *outsh = make_float2((float)sc, (float)((double)be[gc] - mean * sc));
    }
    __syncthreads();
}

// ---- K1: conv1 (1x1x3x3, stride 3x2, VALID) + BN1 partials; blocks 0..63
// also compute vint. x/absmax(x) norm and b1 dropped (absorbed by BN1). ----
__global__ void k_conv1(const float* __restrict__ g, const float* __restrict__ cv,
                        const float* __restrict__ VMM, const float* __restrict__ w1,
                        const float* __restrict__ b1,
                        float* __restrict__ y1, int* __restrict__ vint,
                        double* __restrict__ sums) {
    __shared__ float sm[K1_ROWS * WGN];       // 12 KB
    __shared__ float tt[NP], vv[NP];
    int m  = blockIdx.x >> 4;
    int bg = blockIdx.x & 15;
    const float4* src0 = (const float4*)(g + (size_t)m * TT * WGN
                                           + (size_t)(bg * K1_CH * K1_R * 3) * WGN);
    float w[9];
#pragma unroll
    for (int i = 0; i < 9; i++) w[i] = w1[i];
    float bb = b1[0];
    float4 ra0, ra1, ra2, rb0, rb1, rb2;
    ra0 = src0[threadIdx.x];
    ra1 = src0[threadIdx.x + 256];
    ra2 = src0[threadIdx.x + 512];
    double s = 0, ss = 0;
    float4* dst = (float4*)sm;
#pragma unroll
    for (int i = 0; i < K1_CH; i++) {
        if (i & 1) {
            dst[threadIdx.x]       = rb0;
            dst[threadIdx.x + 256] = rb1;
            dst[threadIdx.x + 512] = rb2;
        } else {
            dst[threadIdx.x]       = ra0;
            dst[threadIdx.x + 256] = ra1;
            dst[threadIdx.x + 512] = ra2;
        }
        __syncthreads();
        if (i + 1 < K1_CH) {
            const float4* srcn = src0 + (size_t)(i + 1) * 768;
            if (i & 1) {
                ra0 = srcn[threadIdx.x];
                ra1 = srcn[threadIdx.x + 256];
                ra2 = srcn[threadIdx.x + 512];
            } else {
                rb0 = srcn[threadIdx.x];
                rb1 = srcn[threadIdx.x + 256];
                rb2 = srcn[threadIdx.x + 512];
            }
        }
        int oh0 = (bg * K1_CH + i) * K1_R;
        float* yb = y1 + (size_t)m * C1H * C1W + (size_t)oh0 * C1W;
        for (int o = threadIdx.x; o < K1_R * C1W; o += 256) {
            int lo = o / C1W, ow = o % C1W;
            const float* xp = sm + (3 * lo) * WGN + ow * 2;
            float acc = bb;
#pragma unroll
            for (int r = 0; r < 3; r++)
#pragma unroll
                for (int c = 0; c < 3; c++) acc += w[r * 3 + c] * xp[r * WGN + c];
            yb[o] = acc;
            s += acc; ss += (double)acc * (double)acc;
        }
        __syncthreads();
    }
    if (blockIdx.x < MM) {
        int mv = blockIdx.x;
        int b = mv >> 3;
        if (threadIdx.x < NP) {
            int n = threadIdx.x;
            float t = cv[(mv * NP + n) * 2 + 0];
            float v = cv[(mv * NP + n) * 2 + 1];
            float dt = 7000.0f / 255.0f;
            tt[n] = t / dt;
            float vmin = VMM[b * 2], vmax = VMM[b * 2 + 1];
            float dv = (vmax - vmin) / 255.0f;
            vv[n] = (v - vmin) / dv;
        }
        __syncthreads();
        int h = threadIdx.x;
        float x = (float)h;
        float val;
        if (x <= tt[0]) val = vv[0];
        else if (x >= tt[NP - 1]) val = vv[NP - 1];
        else {
            int i = 1;
            while (i < NP - 1 && tt[i] <= x) i++;
            float d = tt[i] - tt[i - 1];
            val = (d != 0.f) ? vv[i - 1] + (x - tt[i - 1]) / d * (vv[i] - vv[i - 1]) : vv[i];
        }
        int vi = (int)val;
        vint[mv * HH + h] = max(0, min(WCN - 1, vi));
    }
    blockStore2(s, ss, &sums[P1S], &sums[P1SS]);
}

// ---- K2: BN1-act + maxpool3/5 (separable, LDS) + conv2 + BN2 partials ----
// F2_OH=16 -> 1408 blocks, 20.6 KB LDS: occupancy was the measured bottleneck
// (r6: 26.6% occ, 36% VALU, 10.8us/rep). Rows padded to 33 to de-alias the
// even-bank stride-2 conv reads.
__global__ void k_fused2(const float* __restrict__ y1, const double* __restrict__ sums_r,
                         const float* __restrict__ g1, const float* __restrict__ be1,
                         const float* __restrict__ w2, const float* __restrict__ b2,
                         float* __restrict__ y2, double* __restrict__ sums) {
    __shared__ float sact[F2_NRMAX][F2_PAD];
    __shared__ float sr3[F2_NRMAX][F2_PAD];
    __shared__ float sr5[F2_NRMAX][F2_PAD];
    __shared__ float2 absh;
    bn_fold4(&sums_r[P1S], &sums_r[P1SS], G1, g1, 0, be1, (double)N1, &absh);
    float2 ab1 = absh;
    int m   = blockIdx.x / F2_NCH;
    int ch  = blockIdx.x % F2_NCH;
    int oh0 = ch * F2_OH;
    int OHa = min(F2_OH, C2H - oh0);
    int NR  = 3 * OHa + 4;
    int gl0 = 3 * oh0 - 2;
    const float* yp = y1 + (size_t)m * C1H * C1W;
    for (int i = threadIdx.x; i < NR * C1W; i += blockDim.x) {
        int l = i / C1W, w = i % C1W;
        int gr = gl0 + l;
        float v = -INFINITY;
        if (gr >= 0 && gr < C1H) {
            v = ab1.x * yp[gr * C1W + w] + ab1.y;
            v = v >= 0.f ? v : 0.1f * v;
        }
        sact[l][w] = v;
    }
    __syncthreads();
    for (int i = threadIdx.x; i < NR * C1W; i += blockDim.x) {
        int l = i / C1W, w = i % C1W;
        int wl1 = max(w - 1, 0), wr1 = min(w + 1, C1W - 1);
        int wl2 = max(w - 2, 0), wr2 = min(w + 2, C1W - 1);
        float c  = sact[l][w];
        float m3 = fmaxf(fmaxf(sact[l][wl1], c), sact[l][wr1]);
        float m5 = fmaxf(fmaxf(m3, sact[l][wl2]), sact[l][wr2]);
        sr3[l][w] = m3;
        sr5[l][w] = m5;
    }
    __syncthreads();
    double s0 = 0, ss0 = 0, s1 = 0, ss1 = 0;
    for (int o = threadIdx.x; o < OHa * C2W; o += blockDim.x) {
        int lo = o / C2W, ow = o % C2W;
        float a0 = b2[0], acc1 = b2[1];
#pragma unroll
        for (int i = 0; i < 3; i++) {
            int l = 3 * lo + 2 + i;
#pragma unroll
            for (int j = 0; j < 3; j++) {
                int wc = 2 * ow + j;
                float v0 = sact[l][wc];
                float v1 = fmaxf(fmaxf(sr3[l - 1][wc], sr3[l][wc]), sr3[l + 1][wc]);
                float v2 = fmaxf(fmaxf(fmaxf(sr5[l - 2][wc], sr5[l - 1][wc]), sr5[l][wc]),
                                 fmaxf(sr5[l + 1][wc], sr5[l + 2][wc]));
                int ki = i * 3 + j;
                a0   += w2[ki] * v0 + w2[9 + ki] * v1 + w2[18 + ki] * v2;
                acc1 += w2[27 + ki] * v0 + w2[36 + ki] * v1 + w2[45 + ki] * v2;
            }
        }
        size_t ob = (size_t)m * (2 * C2H * C2W) + (size_t)(oh0 + lo) * C2W + ow;
        y2[ob] = a0;
        y2[ob + C2H * C2W] = acc1;
        s0 += a0; ss0 += (double)a0 * a0;
        s1 += acc1; ss1 += (double)acc1 * acc1;
    }
    blockStore2(s0, ss0, &sums[P2S0], &sums[P2SS0]);
    blockStore2(s1, ss1, &sums[P2S1], &sums[P2SS1]);
}

// ---- K3: conv3 (1x2x3x2, stride 3x2), BN2-act inline + BN3 partials ----
__global__ void k_conv3(const float* __restrict__ y2, const double* __restrict__ sums_r,
                        const float* __restrict__ g2, const float* __restrict__ be2,
                        const float* __restrict__ w3, const float* __restrict__ b3,
                        float* __restrict__ y3, double* __restrict__ sums) {
    __shared__ float2 absh[2];
    bn_fold4(&sums_r[P2S0], &sums_r[P2SS0], G2, g2, 0, be2, (double)N2, &absh[0]);
    bn_fold4(&sums_r[P2S1], &sums_r[P2SS1], G2, g2, 1, be2, (double)N2, &absh[1]);
    float2 ab20 = absh[0], ab21 = absh[1];
    double s = 0, ss = 0;
    int idx = blockIdx.x * 256 + threadIdx.x;
    if (idx < N3) {
        int ow = idx % C3W;
        int t2 = idx / C3W;
        int oh = t2 % C3H;
        int m  = t2 / C3H;
        float acc = b3[0];
#pragma unroll
        for (int i = 0; i < 2; i++) {
            float aa = i ? ab21.x : ab20.x, bb = i ? ab21.y : ab20.y;
            const float* cp = y2 + (size_t)m * (2 * C2H * C2W) + (size_t)i * C2H * C2W
                              + (size_t)(oh * 3) * C2W + ow * 2;
#pragma unroll
            for (int r = 0; r < 3; r++)
#pragma unroll
                for (int c = 0; c < 2; c++) {
                    float v = aa * cp[r * C2W + c] + bb;
                    v = v >= 0.f ? v : 0.1f * v;
                    acc += w3[i * 6 + r * 2 + c] * v;
                }
        }
        y3[idx] = acc;
        s = acc; ss = (double)acc * acc;
    }
    blockStore2(s, ss, &sums[P3S], &sums[P3SS]);
}

// ---- K5a: genr-on-the-fly -> mix tile -> convf -> y5 + BNf partials ----
// MC_TH=8 -> 1024 blocks, 20.6 KB LDS (2x occupancy vs r5's 37 KB tiles).
__global__ void k_mixA(const float* __restrict__ y3, const int* __restrict__ vint,
                       const double* __restrict__ sums_r,
                       const float* __restrict__ g3, const float* __restrict__ be3,
                       const float* __restrict__ wf, const float* __restrict__ bf,
                       float* __restrict__ y5, double* __restrict__ sums) {
    __shared__ float tile[MC_TH + 2][RWN + 2];
    __shared__ float Grow[MC_TH + 2];
    __shared__ float2 absh;
    bn_fold4(&sums_r[P3S], &sums_r[P3SS], G3, g3, 0, be3, (double)N3, &absh);
    float2 ab3 = absh;
    int b   = blockIdx.x / (RHN / MC_TH);
    int h0  = (blockIdx.x % (RHN / MC_TH)) * MC_TH;
    for (int i = threadIdx.x; i < (MC_TH + 2) * (RWN + 2); i += 256)
        ((float*)tile)[i] = 0.f;
    if (threadIdx.x < MC_TH + 2) Grow[threadIdx.x] = 0.f;
    __syncthreads();
    if (threadIdx.x < (MC_TH + 2) * KG) {
        int r = threadIdx.x / KG, k = threadIdx.x % KG;
        int h = h0 - 1 + r;
        if (h >= 0 && h < RHN) {
            int m = b * KG + k;
            const float cw0 = 4.f / 37.f, cw1 = 5.f / 37.f, cw2 = 6.f / 37.f, cw3 = 7.f / 37.f;
            const float cw[7] = { cw0, cw1, cw2, cw3, cw2, cw1, cw0 };
            float shg = (h + 0.5f) * (113.0f / 1024.0f) - 0.5f;
            float flg = floorf(shg);
            float frg = shg - flg;
            int gi0 = (int)flg, gi1 = gi0 + 1;
            gi0 = max(0, min(C3H - 1, gi0));
            gi1 = max(0, min(C3H - 1, gi1));
            const float* yp0 = y3 + (size_t)m * (C3H * C3W) + gi0 * C3W;
            const float* yp1 = y3 + (size_t)m * (C3H * C3W) + gi1 * C3W;
            float g = 0.f;
#pragma unroll
            for (int x = 0; x < 7; x++) {
                float t0 = ab3.x * yp0[x] + ab3.y;
                t0 = t0 >= 0.f ? t0 : 0.1f * t0;
                float t1 = ab3.x * yp1[x] + ab3.y;
                t1 = t1 >= 0.f ? t1 : 0.1f * t1;
                g += cw[x] * ((1.f - frg) * t0 + frg * t1);
            }
            atomicAdd(&Grow[r], g);
            float sh = (h + 0.5f) * 0.25f - 0.5f;
            float fl = floorf(sh);
            float fh = sh - fl;
            int ih0 = (int)fl, ih1 = ih0 + 1;
            ih0 = max(0, min(HH - 1, ih0));
            ih1 = max(0, min(HH - 1, ih1));
            int vv2[2] = { vint[m * HH + ih0], vint[m * HH + ih1] };
            float aa[2] = { 0.9f * g * (1.f - fh), 0.9f * g * fh };
#pragma unroll
            for (int t = 0; t < 2; t++) {
                int v = vv2[t]; float A = aa[t];
                if (v == 0) {
                    atomicAdd(&tile[r][1 + 0], A);
                    atomicAdd(&tile[r][1 + 1], 0.75f * A);
                    atomicAdd(&tile[r][1 + 2], 0.25f * A);
                } else if (v == WCN - 1) {
                    atomicAdd(&tile[r][1 + 509], 0.25f * A);
                    atomicAdd(&tile[r][1 + 510], 0.75f * A);
                    atomicAdd(&tile[r][1 + 511], A);
                } else {
                    atomicAdd(&tile[r][1 + 2 * v - 1], 0.25f * A);
                    atomicAdd(&tile[r][1 + 2 * v],     0.75f * A);
                    atomicAdd(&tile[r][1 + 2 * v + 1], 0.75f * A);
                    atomicAdd(&tile[r][1 + 2 * v + 2], 0.25f * A);
                }
            }
        }
    }
    __syncthreads();
    for (int i = threadIdx.x; i < (MC_TH + 2) * RWN; i += 256) {
        int r = i / RWN, w = i % RWN;
        int h = h0 - 1 + r;
        if (h >= 0 && h < RHN) tile[r][w + 1] += 0.01f * Grow[r];
    }
    __syncthreads();
    float w[9];
#pragma unroll
    for (int i = 0; i < 9; i++) w[i] = wf[i];
    float bb = bf[0];
    double s = 0, ss = 0;
    for (int o = threadIdx.x; o < MC_TH * RWN; o += 256) {
        int lr = o >> 9, x = o & (RWN - 1);
        float acc = bb;
#pragma unroll
        for (int dr = 0; dr < 3; dr++)
#pragma unroll
            for (int dc = 0; dc < 3; dc++)
                acc += w[dr * 3 + dc] * tile[lr + dr][x + dc];
        y5[((size_t)b * RHN + (h0 + lr)) * RWN + x] = acc;
        s += acc; ss += (double)acc * acc;
    }
    blockStore2(s, ss, &sums[PFS], &sums[PFSS]);
}

// ---- K5b: BNf affine + LReLU over y5 -> out (vectorized) ----
__global__ void k_bnf(const float* __restrict__ y5, const double* __restrict__ sums_r,
                      const float* __restrict__ gf, const float* __restrict__ bef,
                      float* __restrict__ out) {
    __shared__ float2 absh;
    bn_fold4(&sums_r[PFS], &sums_r[PFSS], G5, gf, 0, bef, (double)NF, &absh);
    float2 abf = absh;
    const float4* src = (const float4*)y5;
    float4* dst = (float4*)out;
    int base = blockIdx.x * 256 + threadIdx.x;
#pragma unroll
    for (int j = 0; j < 8; j++) {
        int i = base + j * (G6 * 256);
        float4 v = src[i];
        float a0 = abf.x * v.x + abf.y;
        float a1 = abf.x * v.y + abf.y;
        float a2 = abf.x * v.z + abf.y;
        float a3 = abf.x * v.w + abf.y;
        v.x = a0 >= 0.f ? a0 : 0.1f * a0;
        v.y = a1 >= 0.f ? a1 : 0.1f * a1;
        v.z = a2 >= 0.f ? a2 : 0.1f * a2;
        v.w = a3 >= 0.f ? a3 : 0.1f * a3;
        dst[i] = v;
    }
}

extern "C" void kernel_launch(void* const* d_in, const int* in_sizes, int n_in,
                              void* d_out, int out_size, void* d_ws, size_t ws_size,
                              hipStream_t stream) {
    const float* gather = (const float*)d_in[0];
    const float* cv     = (const float*)d_in[1];
    const float* VMM    = (const float*)d_in[2];
    const float* w1 = (const float*)d_in[3];
    const float* b1 = (const float*)d_in[4];
    const float* g1 = (const float*)d_in[5];
    const float* be1 = (const float*)d_in[6];
    const float* w2 = (const float*)d_in[7];
    const float* b2 = (const float*)d_in[8];
    const float* g2 = (const float*)d_in[9];
    const float* be2 = (const float*)d_in[10];
    const float* w3 = (const float*)d_in[11];
    const float* b3 = (const float*)d_in[12];
    const float* g3 = (const float*)d_in[13];
    const float* be3 = (const float*)d_in[14];
    const float* wf = (const float*)d_in[15];
    const float* bf = (const float*)d_in[16];
    const float* gf = (const float*)d_in[17];
    const float* bef = (const float*)d_in[18];
    float* out = (float*)d_out;

    char* ws = (char*)d_ws;
    double* sums = (double*)ws;
    int*   vint  = (int*)(ws + OFF_VINT);
    float* y1    = (float*)(ws + OFF_Y1);
    float* y2    = (float*)(ws + OFF_Y2);
    float* y3    = (float*)(ws + OFF_Y3);
    float* y5    = (float*)(ws + OFF_Y5);

    k_conv1<<<G1, 256, 0, stream>>>(gather, cv, VMM, w1, b1, y1, vint, sums);
    k_fused2<<<G2, 256, 0, stream>>>(y1, sums, g1, be1, w2, b2, y2, sums);
    k_conv3<<<G3, 256, 0, stream>>>(y2, sums, g2, be2, w3, b3, y3, sums);
    k_mixA<<<G5, 256, 0, stream>>>(y3, vint, sums, g3, be3, wf, bf, y5, sums);
    k_bnf<<<G6, 256, 0, stream>>>(y5, sums, gf, bef, out);
}